// Round 12
// baseline (43.276 us; speedup 1.0000x reference)
//
#include <hip/hip_runtime.h>

typedef __bf16 bf16x8 __attribute__((ext_vector_type(8)));
typedef float f32x16 __attribute__((ext_vector_type(16)));
typedef float f32x4 __attribute__((ext_vector_type(4)));

#define S_TOTAL 8192
#define DIM 256
#define BK 16
#define SPLIT 16

// R12: split=16 (ws round-trip 64->32 MB, the dominant slack at R11's ~84%-of-
// ceiling effective BW). Block = (batch, sp, jhalf) computes a 256x128 partial
// slice over kc=512. 512 thr = 8 waves (4x2 of 64x64, 64 AGPR acc). Staging is
// pure global_load_lds DMA (zero staging VGPRs) into QUADRUPLE-buffered f32
// LDS (A 16KB + B 8KB per buf, 96KB/block), prefetch depth 3, counted
// vmcnt(6/3/0), one barrier/iter (buffer (it+3)%4 == (it-1)%4 whose compute
// finished before barrier #it -> race-free). XCD-pair swizzle co-locates the
// jhalf pair on one XCD so the duplicated A-panel read is L2-served (R11:
// FETCH unchanged vs no-dup).
__global__ __launch_bounds__(512, 4) void opm_partial(
    const float* __restrict__ A, const float* __restrict__ Bm,
    __bf16* __restrict__ dstbf, float* __restrict__ dstf32,
    int split, int kc, float scale)
{
    __shared__ float lA[4][BK * 256];   // 4 x 16 KB
    __shared__ float lB[4][BK * 128];   // 4 x 8 KB

    const int tid = threadIdx.x;
    const int w   = tid >> 6;            // 0..7
    const int l   = tid & 63;

    // XCD-pair swizzle: bid = x + 8*(2q + m) -> pair p = q*8+x on XCD x.
    const int bid = blockIdx.x;
    const int x  = bid & 7;
    const int k  = bid >> 3;
    const int jh = k & 1;
    const int p  = (k >> 1) * 8 + x;
    const int batch = p / split;
    const int sp    = p % split;

    const long long base = (long long)batch * S_TOTAL * DIM;
    const int s0 = sp * kc;
    const int wr = w >> 1, wc = w & 1;   // wave position in 4x2 grid
    const int lane31 = l & 31;
    const int hi = l >> 5;
    const int niter = kc / BK;

    f32x16 acc[2][2] = {};

    // DMA slots per wave: A rows {w, w+8}, B row-pair {2w, 2w+1}. 3 instrs/wave.
    auto issue = [&](int it) {
        const int b4 = it & 3;
        const long long sb = (long long)(s0 + it * BK);
        __builtin_amdgcn_global_load_lds(
            (const __attribute__((address_space(1))) unsigned int*)(A + base + (sb + w) * DIM + 4 * l),
            (__attribute__((address_space(3))) unsigned int*)&lA[b4][w * 256], 16, 0, 0);
        __builtin_amdgcn_global_load_lds(
            (const __attribute__((address_space(1))) unsigned int*)(A + base + (sb + w + 8) * DIM + 4 * l),
            (__attribute__((address_space(3))) unsigned int*)&lA[b4][(w + 8) * 256], 16, 0, 0);
        __builtin_amdgcn_global_load_lds(
            (const __attribute__((address_space(1))) unsigned int*)(Bm + base + (sb + 2 * w + (l >> 5)) * DIM + jh * 128 + 4 * (l & 31)),
            (__attribute__((address_space(3))) unsigned int*)&lB[b4][2 * w * 128], 16, 0, 0);
    };

    auto compute = [&](int b4) {
        const int i0 = wr * 64 + lane31;
        const int j0 = wc * 64 + lane31;
        bf16x8 af[2], bfv[2];
        #pragma unroll
        for (int mi = 0; mi < 2; ++mi)
            #pragma unroll
            for (int e = 0; e < 8; ++e)
                af[mi][e] = (__bf16)lA[b4][(hi * 8 + e) * 256 + i0 + mi * 32];
        #pragma unroll
        for (int nj = 0; nj < 2; ++nj)
            #pragma unroll
            for (int e = 0; e < 8; ++e)
                bfv[nj][e] = (__bf16)lB[b4][(hi * 8 + e) * 128 + j0 + nj * 32];
        #pragma unroll
        for (int mi = 0; mi < 2; ++mi)
            #pragma unroll
            for (int nj = 0; nj < 2; ++nj)
                acc[mi][nj] = __builtin_amdgcn_mfma_f32_32x32x16_bf16(
                    af[mi], bfv[nj], acc[mi][nj], 0, 0, 0);
    };

    // prologue: T0..T2 in flight (9 VMEM instrs/wave outstanding at peak)
    issue(0);
    issue(1);
    issue(2);

    for (int it = 0; it < niter; ++it) {
        // outstanding tiles at top of iter: it..min(it+2, niter-1)
        if (it + 3 <= niter)      asm volatile("s_waitcnt vmcnt(6)" ::: "memory");
        else if (it + 2 == niter) asm volatile("s_waitcnt vmcnt(3)" ::: "memory");
        else                      asm volatile("s_waitcnt vmcnt(0)" ::: "memory");
        __builtin_amdgcn_s_barrier();            // all waves' slots for T_it landed
        if (it + 3 < niter) issue(it + 3);       // buf (it+3)&3 == (it-1)&3: compute done
        compute(it & 3);
    }

    // ---- epilogue: 256x128 slice ----
    if (dstf32) {
        float* o = dstf32 + (long long)batch * (256 * 256) + jh * 128;
        #pragma unroll
        for (int mi = 0; mi < 2; ++mi)
        #pragma unroll
        for (int nj = 0; nj < 2; ++nj)
        #pragma unroll
        for (int q = 0; q < 16; ++q) {
            const int row = (q & 3) + 8 * (q >> 2) + 4 * hi;
            const int i = wr * 64 + mi * 32 + row;
            const int j = wc * 64 + nj * 32 + lane31;
            o[i * 256 + j] = acc[mi][nj][q] * scale;
        }
    } else {
        // band-repack through (now dead) lA, then coalesced bf16x8 stores
        __bf16* o = dstbf + (long long)(batch * split + sp) * (256 * 256) + jh * 128;
        __bf16* ebuf = (__bf16*)&lA[0][0];       // 16 KB band: 64 rows x 128 cols
        #pragma unroll
        for (int band = 0; band < 4; ++band) {
            __syncthreads();
            if (wr == band) {
                #pragma unroll
                for (int mi = 0; mi < 2; ++mi)
                #pragma unroll
                for (int nj = 0; nj < 2; ++nj)
                #pragma unroll
                for (int q = 0; q < 16; ++q) {
                    const int row = mi * 32 + (q & 3) + 8 * (q >> 2) + 4 * hi;
                    const int col = wc * 64 + nj * 32 + lane31;
                    ebuf[row * 128 + col] = (__bf16)(acc[mi][nj][q] * scale);
                }
            }
            __syncthreads();
            #pragma unroll
            for (int h = 0; h < 2; ++h) {
                const int G = tid + h * 512;
                const int r = G >> 4, c8 = (G & 15) * 8;
                bf16x8 v = *(const bf16x8*)&ebuf[r * 128 + c8];
                *(bf16x8*)&o[(band * 64 + r) * 256 + c8] = v;
            }
        }
    }
}

// Fully-unrolled reduce (R10-proven): SPLIT independent bf16x8 loads -> BW-bound.
__global__ __launch_bounds__(256) void opm_reduceN(
    const __bf16* __restrict__ ws, float* __restrict__ out)
{
    const int idx = blockIdx.x * 256 + threadIdx.x;
    const int b = idx >> 13;
    const int r = idx & 8191;
    const bf16x8* p = (const bf16x8*)ws + ((long long)b * SPLIT) * 8192 + r;

    bf16x8 v[SPLIT];
    #pragma unroll
    for (int sp = 0; sp < SPLIT; ++sp) v[sp] = p[sp * 8192];

    float s[8] = {0.f, 0.f, 0.f, 0.f, 0.f, 0.f, 0.f, 0.f};
    #pragma unroll
    for (int sp = 0; sp < SPLIT; ++sp)
        #pragma unroll
        for (int e = 0; e < 8; ++e) s[e] += (float)v[sp][e];

    f32x4 lo = { s[0], s[1], s[2], s[3] };
    f32x4 hiv = { s[4], s[5], s[6], s[7] };
    lo  *= (1.0f / 8192.0f);
    hiv *= (1.0f / 8192.0f);
    ((f32x4*)out)[idx * 2]     = lo;
    ((f32x4*)out)[idx * 2 + 1] = hiv;
}

extern "C" void kernel_launch(void* const* d_in, const int* in_sizes, int n_in,
                              void* d_out, int out_size, void* d_ws, size_t ws_size,
                              hipStream_t stream)
{
    (void)in_sizes; (void)n_in; (void)out_size;
    const float* A  = (const float*)d_in[0];
    const float* Bm = (const float*)d_in[1];
    float* out = (float*)d_out;

    if (ws_size >= (size_t)8 * SPLIT * 65536 * sizeof(__bf16)) {
        opm_partial<<<16 * SPLIT, 512, 0, stream>>>(A, Bm, (__bf16*)d_ws, nullptr,
                                                    SPLIT, S_TOTAL / SPLIT, 1.0f);
        opm_reduceN<<<256, 256, 0, stream>>>((const __bf16*)d_ws, out);
    } else {
        // tiny-ws fallback: 16 blocks (8 batches x 2 jhalves) over full K, f32 direct
        opm_partial<<<16, 512, 0, stream>>>(A, Bm, nullptr, out, 1, S_TOTAL, 1.0f / 8192.0f);
    }
}

// Round 13
// 41.530 us; speedup vs baseline: 1.0420x; 1.0420x over previous
//
#include <hip/hip_runtime.h>

typedef __bf16 bf16x8 __attribute__((ext_vector_type(8)));
typedef float f32x16 __attribute__((ext_vector_type(16)));
typedef float f32x4 __attribute__((ext_vector_type(4)));

#define S_TOTAL 8192
#define DIM 256
#define BK 16
#define NSP 16

// R13: Block = (batch, sp in 0..nsp-1, jq in 0..3) computes a 256x64 partial
// slice over kc = S/nsp. 512 thr = 8 waves (4x2 grid; wave tile 64x32, 32 AGPR).
// R11's proven pipeline: 3-buf f32 LDS (A 16KB + B 4KB per buf = 60KB),
// global_load_lds DMA only (zero staging VGPRs), depth-2 prefetch, counted
// vmcnt, one barrier/iter. 2 blocks/CU (120KB LDS, low regs).
// ws halved vs R11 (16MB): nsp=16. The 4 jq-mates share their A-chunk via the
// XCD swizzle (g = g_x*8 + x keeps mates on one XCD; R11 measured +0 FETCH for
// this dedup mechanism).
__global__ __launch_bounds__(512, 4) void opm_partial(
    const float* __restrict__ A, const float* __restrict__ Bm,
    __bf16* __restrict__ dstbf, float* __restrict__ dstf32,
    int nsp, int kc, float scale)
{
    __shared__ float lA[3][BK * 256];   // 3 x 16 KB
    __shared__ float lB[3][BK * 64];    // 3 x 4 KB

    const int tid = threadIdx.x;
    const int w   = tid >> 6;            // 0..7
    const int l   = tid & 63;

    // swizzle: bid = x + 8*(g_x*4 + jq); group g = g_x*8 + x (4 jq-mates per g on XCD x)
    const int bid = blockIdx.x;
    const int x   = bid & 7;
    const int s   = bid >> 3;
    const int jq  = s & 3;
    const int gx  = s >> 2;
    const int g   = gx * 8 + x;
    const int batch = g / nsp;
    const int sp    = g % nsp;

    const long long base = (long long)batch * S_TOTAL * DIM;
    const int s0 = sp * kc;
    const int wr = w >> 1, wc = w & 1;   // 4x2 wave grid
    const int lane31 = l & 31;
    const int hi = l >> 5;
    const int niter = kc / BK;

    f32x16 acc[2] = {};                  // mi = 0,1 (rows +0,+32); 32 AGPR

    // DMA per tile: every wave 2 A-row instrs (rows w, w+8); waves 0-3 one
    // B instr covering rows 4w..4w+3 of the 64-wide j-quarter.
    auto issue = [&](int it) {
        const int b3 = it % 3;
        const long long sb = (long long)(s0 + it * BK);
        __builtin_amdgcn_global_load_lds(
            (const __attribute__((address_space(1))) unsigned int*)(A + base + (sb + w) * DIM + 4 * l),
            (__attribute__((address_space(3))) unsigned int*)&lA[b3][w * 256], 16, 0, 0);
        __builtin_amdgcn_global_load_lds(
            (const __attribute__((address_space(1))) unsigned int*)(A + base + (sb + w + 8) * DIM + 4 * l),
            (__attribute__((address_space(3))) unsigned int*)&lA[b3][(w + 8) * 256], 16, 0, 0);
        if (w < 4) {
            __builtin_amdgcn_global_load_lds(
                (const __attribute__((address_space(1))) unsigned int*)(Bm + base + (sb + 4 * w + (l >> 4)) * DIM + jq * 64 + 4 * (l & 15)),
                (__attribute__((address_space(3))) unsigned int*)&lB[b3][4 * w * 64], 16, 0, 0);
        }
    };

    auto compute = [&](int b3) {
        const int i0 = wr * 64 + lane31;
        const int j0 = wc * 32 + lane31;
        bf16x8 af[2], bfv;
        #pragma unroll
        for (int mi = 0; mi < 2; ++mi)
            #pragma unroll
            for (int e = 0; e < 8; ++e)
                af[mi][e] = (__bf16)lA[b3][(hi * 8 + e) * 256 + i0 + mi * 32];
        #pragma unroll
        for (int e = 0; e < 8; ++e)
            bfv[e] = (__bf16)lB[b3][(hi * 8 + e) * 64 + j0];
        acc[0] = __builtin_amdgcn_mfma_f32_32x32x16_bf16(af[0], bfv, acc[0], 0, 0, 0);
        acc[1] = __builtin_amdgcn_mfma_f32_32x32x16_bf16(af[1], bfv, acc[1], 0, 0, 0);
    };

    issue(0);
    issue(1);

    for (int it = 0; it < niter; ++it) {
        const int rem = niter - 1 - it;     // tiles outstanding beyond T_it
        if (w < 4) {                        // 3 VMEM instrs/tile on these waves
            if (rem >= 1) asm volatile("s_waitcnt vmcnt(3)" ::: "memory");
            else          asm volatile("s_waitcnt vmcnt(0)" ::: "memory");
        } else {                            // 2 VMEM instrs/tile
            if (rem >= 1) asm volatile("s_waitcnt vmcnt(2)" ::: "memory");
            else          asm volatile("s_waitcnt vmcnt(0)" ::: "memory");
        }
        __builtin_amdgcn_s_barrier();       // T_it fully landed for all waves
        if (it + 2 < niter) issue(it + 2);  // buf (it+2)%3 == (it-1)%3: consumed
        compute(it % 3);
    }

    // ---- epilogue: 256x64 slice, contiguous [256][64] per tile ----
    if (dstf32) {
        float* o = dstf32 + (long long)batch * (256 * 256) + jq * 64;
        #pragma unroll
        for (int mi = 0; mi < 2; ++mi)
        #pragma unroll
        for (int q = 0; q < 16; ++q) {
            const int row = (q & 3) + 8 * (q >> 2) + 4 * hi;
            const int i = wr * 64 + mi * 32 + row;
            const int j = wc * 32 + lane31;
            o[i * 256 + j] = acc[mi][q] * scale;
        }
    } else {
        __bf16* o = dstbf + (long long)((batch * nsp + sp) * 4 + jq) * 16384;
        __bf16* ebuf = (__bf16*)&lA[0][0];   // 16 KB band: 128 rows x 64 cols
        #pragma unroll
        for (int band = 0; band < 2; ++band) {
            __syncthreads();
            if ((wr >> 1) == band) {
                #pragma unroll
                for (int mi = 0; mi < 2; ++mi)
                #pragma unroll
                for (int q = 0; q < 16; ++q) {
                    const int lr = (wr & 1) * 64 + mi * 32 + (q & 3) + 8 * (q >> 2) + 4 * hi;
                    ebuf[lr * 64 + wc * 32 + lane31] = (__bf16)(acc[mi][q] * scale);
                }
            }
            __syncthreads();
            #pragma unroll
            for (int h = 0; h < 2; ++h) {
                const int G = tid + h * 512;        // 1024 bf16x8 groups / band
                *(bf16x8*)&o[band * 8192 + G * 8] = *(const bf16x8*)&ebuf[G * 8];
            }
        }
    }
}

// Sum NSP=16 bf16 partials, scale by 1/8192. Fully unrolled (R10-proven).
// ws layout: tile ((batch*16+sp)*4+jq) is a contiguous [256][64] slice.
__global__ __launch_bounds__(256) void opm_reduce16(
    const __bf16* __restrict__ ws, float* __restrict__ out)
{
    const int idx = blockIdx.x * 256 + threadIdx.x;  // 65536 bf16x8 groups
    const int batch = idx >> 13;
    const int gg  = idx & 8191;
    const int i   = gg >> 5;
    const int jgc = gg & 31;
    const int jq  = jgc >> 3;
    const int c8  = (jgc & 7) * 8;

    const bf16x8* p = (const bf16x8*)(ws + ((long long)(batch * NSP) * 4 + jq) * 16384 + i * 64 + c8);
    // sp stride = 4*16384 bf16 = 8192 bf16x8 groups
    bf16x8 v[NSP];
    #pragma unroll
    for (int sp = 0; sp < NSP; ++sp) v[sp] = p[sp * 8192];

    float sacc[8] = {0.f, 0.f, 0.f, 0.f, 0.f, 0.f, 0.f, 0.f};
    #pragma unroll
    for (int sp = 0; sp < NSP; ++sp)
        #pragma unroll
        for (int e = 0; e < 8; ++e) sacc[e] += (float)v[sp][e];

    f32x4 lo = { sacc[0], sacc[1], sacc[2], sacc[3] };
    f32x4 hiv = { sacc[4], sacc[5], sacc[6], sacc[7] };
    lo  *= (1.0f / 8192.0f);
    hiv *= (1.0f / 8192.0f);
    ((f32x4*)out)[idx * 2]     = lo;
    ((f32x4*)out)[idx * 2 + 1] = hiv;
}

extern "C" void kernel_launch(void* const* d_in, const int* in_sizes, int n_in,
                              void* d_out, int out_size, void* d_ws, size_t ws_size,
                              hipStream_t stream)
{
    (void)in_sizes; (void)n_in; (void)out_size;
    const float* A  = (const float*)d_in[0];
    const float* Bm = (const float*)d_in[1];
    float* out = (float*)d_out;

    if (ws_size >= (size_t)8 * NSP * 4 * 16384 * sizeof(__bf16)) {   // 16 MB
        opm_partial<<<32 * NSP, 512, 0, stream>>>(A, Bm, (__bf16*)d_ws, nullptr,
                                                  NSP, S_TOTAL / NSP, 1.0f);
        opm_reduce16<<<256, 256, 0, stream>>>((const __bf16*)d_ws, out);
    } else {
        // tiny-ws fallback: 32 blocks (8 batch x 4 jq), full K, f32 direct
        opm_partial<<<32, 512, 0, stream>>>(A, Bm, nullptr, out, 1, S_TOTAL, 1.0f / 8192.0f);
    }
}

// Round 14
// 39.686 us; speedup vs baseline: 1.0905x; 1.0465x over previous
//
#include <hip/hip_runtime.h>

typedef __bf16 bf16x8 __attribute__((ext_vector_type(8)));
typedef float f32x16 __attribute__((ext_vector_type(16)));
typedef float f32x4 __attribute__((ext_vector_type(4)));

#define S_TOTAL 8192
#define DIM 256
#define BK 16
#define NSP 16

// R14 = R13 with 2-buf LDS (40KB) + launch_bounds(512,6) -> 3 blocks/CU =
// 24 waves/CU (TLP test: every prior variant ran <=16 waves/CU at ~5.3TB/s
// effective; the 6.3TB/s copy ceiling was measured at ~32 waves/CU).
// Block = (batch, sp, jq): 256x64 partial slice, kc = S/NSP. 8 waves
// (4x2; wave tile 64x32, 32 AGPR). Staging pure global_load_lds DMA.
// 2-buf pipeline: issue T_{it+1} right after barrier #it (its buffer was
// consumed before that barrier -> race-free), lands during compute(it).
__global__ __launch_bounds__(512, 6) void opm_partial(
    const float* __restrict__ A, const float* __restrict__ Bm,
    __bf16* __restrict__ dstbf, float* __restrict__ dstf32,
    int nsp, int kc, float scale)
{
    __shared__ float lA[2][BK * 256];   // 2 x 16 KB
    __shared__ float lB[2][BK * 64];    // 2 x 4 KB

    const int tid = threadIdx.x;
    const int w   = tid >> 6;            // 0..7
    const int l   = tid & 63;

    // swizzle: bid = x + 8*(g_x*4 + jq); group g = g_x*8 + x (4 jq-mates on XCD x)
    const int bid = blockIdx.x;
    const int x   = bid & 7;
    const int s   = bid >> 3;
    const int jq  = s & 3;
    const int gx  = s >> 2;
    const int g   = gx * 8 + x;
    const int batch = g / nsp;
    const int sp    = g % nsp;

    const long long base = (long long)batch * S_TOTAL * DIM;
    const int s0 = sp * kc;
    const int wr = w >> 1, wc = w & 1;   // 4x2 wave grid
    const int lane31 = l & 31;
    const int hi = l >> 5;
    const int niter = kc / BK;           // 32

    f32x16 acc[2] = {};                  // 32 AGPR

    // DMA per tile: every wave 2 A-row instrs (rows w, w+8); waves 0-3 one
    // B instr covering rows 4w..4w+3 of the 64-wide j-quarter.
    auto issue = [&](int it) {
        const int b2 = it & 1;
        const long long sb = (long long)(s0 + it * BK);
        __builtin_amdgcn_global_load_lds(
            (const __attribute__((address_space(1))) unsigned int*)(A + base + (sb + w) * DIM + 4 * l),
            (__attribute__((address_space(3))) unsigned int*)&lA[b2][w * 256], 16, 0, 0);
        __builtin_amdgcn_global_load_lds(
            (const __attribute__((address_space(1))) unsigned int*)(A + base + (sb + w + 8) * DIM + 4 * l),
            (__attribute__((address_space(3))) unsigned int*)&lA[b2][(w + 8) * 256], 16, 0, 0);
        if (w < 4) {
            __builtin_amdgcn_global_load_lds(
                (const __attribute__((address_space(1))) unsigned int*)(Bm + base + (sb + 4 * w + (l >> 4)) * DIM + jq * 64 + 4 * (l & 15)),
                (__attribute__((address_space(3))) unsigned int*)&lB[b2][4 * w * 64], 16, 0, 0);
        }
    };

    auto compute = [&](int b2) {
        const int i0 = wr * 64 + lane31;
        const int j0 = wc * 32 + lane31;
        bf16x8 af[2], bfv;
        #pragma unroll
        for (int mi = 0; mi < 2; ++mi)
            #pragma unroll
            for (int e = 0; e < 8; ++e)
                af[mi][e] = (__bf16)lA[b2][(hi * 8 + e) * 256 + i0 + mi * 32];
        #pragma unroll
        for (int e = 0; e < 8; ++e)
            bfv[e] = (__bf16)lB[b2][(hi * 8 + e) * 64 + j0];
        acc[0] = __builtin_amdgcn_mfma_f32_32x32x16_bf16(af[0], bfv, acc[0], 0, 0, 0);
        acc[1] = __builtin_amdgcn_mfma_f32_32x32x16_bf16(af[1], bfv, acc[1], 0, 0, 0);
    };

    // prologue: T0, T1 in flight (buffers 0 and 1, both free)
    issue(0);
    issue(1);

    for (int it = 0; it < niter; ++it) {
        // wait for T_it; at it==0, T1 is also outstanding (3 or 2 instrs/wave)
        if (it == 0) {
            if (w < 4) asm volatile("s_waitcnt vmcnt(3)" ::: "memory");
            else       asm volatile("s_waitcnt vmcnt(2)" ::: "memory");
        } else {
            asm volatile("s_waitcnt vmcnt(0)" ::: "memory");
        }
        __builtin_amdgcn_s_barrier();            // all waves' T_it slots landed
        if (it >= 1 && it + 1 < niter) issue(it + 1);  // buf (it+1)&1: consumed pre-barrier
        compute(it & 1);
    }

    // ---- epilogue: 256x64 slice, contiguous [256][64] per tile ----
    if (dstf32) {
        float* o = dstf32 + (long long)batch * (256 * 256) + jq * 64;
        #pragma unroll
        for (int mi = 0; mi < 2; ++mi)
        #pragma unroll
        for (int q = 0; q < 16; ++q) {
            const int row = (q & 3) + 8 * (q >> 2) + 4 * hi;
            const int i = wr * 64 + mi * 32 + row;
            const int j = wc * 32 + lane31;
            o[i * 256 + j] = acc[mi][q] * scale;
        }
    } else {
        __bf16* o = dstbf + (long long)((batch * nsp + sp) * 4 + jq) * 16384;
        __bf16* ebuf = (__bf16*)&lA[0][0];   // 16 KB band: 128 rows x 64 cols
        #pragma unroll
        for (int band = 0; band < 2; ++band) {
            __syncthreads();
            if ((wr >> 1) == band) {
                #pragma unroll
                for (int mi = 0; mi < 2; ++mi)
                #pragma unroll
                for (int q = 0; q < 16; ++q) {
                    const int lr = (wr & 1) * 64 + mi * 32 + (q & 3) + 8 * (q >> 2) + 4 * hi;
                    ebuf[lr * 64 + wc * 32 + lane31] = (__bf16)(acc[mi][q] * scale);
                }
            }
            __syncthreads();
            #pragma unroll
            for (int h = 0; h < 2; ++h) {
                const int G = tid + h * 512;        // 1024 bf16x8 groups / band
                *(bf16x8*)&o[band * 8192 + G * 8] = *(const bf16x8*)&ebuf[G * 8];
            }
        }
    }
}

// Sum NSP=16 bf16 partials, scale by 1/8192. Fully unrolled (R10-proven).
// ws layout: tile ((batch*16+sp)*4+jq) is a contiguous [256][64] slice.
__global__ __launch_bounds__(256) void opm_reduce16(
    const __bf16* __restrict__ ws, float* __restrict__ out)
{
    const int idx = blockIdx.x * 256 + threadIdx.x;  // 65536 bf16x8 groups
    const int batch = idx >> 13;
    const int gg  = idx & 8191;
    const int i   = gg >> 5;
    const int jgc = gg & 31;
    const int jq  = jgc >> 3;
    const int c8  = (jgc & 7) * 8;

    const bf16x8* p = (const bf16x8*)(ws + ((long long)(batch * NSP) * 4 + jq) * 16384 + i * 64 + c8);
    bf16x8 v[NSP];
    #pragma unroll
    for (int sp = 0; sp < NSP; ++sp) v[sp] = p[sp * 8192];

    float sacc[8] = {0.f, 0.f, 0.f, 0.f, 0.f, 0.f, 0.f, 0.f};
    #pragma unroll
    for (int sp = 0; sp < NSP; ++sp)
        #pragma unroll
        for (int e = 0; e < 8; ++e) sacc[e] += (float)v[sp][e];

    f32x4 lo = { sacc[0], sacc[1], sacc[2], sacc[3] };
    f32x4 hiv = { sacc[4], sacc[5], sacc[6], sacc[7] };
    lo  *= (1.0f / 8192.0f);
    hiv *= (1.0f / 8192.0f);
    ((f32x4*)out)[idx * 2]     = lo;
    ((f32x4*)out)[idx * 2 + 1] = hiv;
}

extern "C" void kernel_launch(void* const* d_in, const int* in_sizes, int n_in,
                              void* d_out, int out_size, void* d_ws, size_t ws_size,
                              hipStream_t stream)
{
    (void)in_sizes; (void)n_in; (void)out_size;
    const float* A  = (const float*)d_in[0];
    const float* Bm = (const float*)d_in[1];
    float* out = (float*)d_out;

    if (ws_size >= (size_t)8 * NSP * 4 * 16384 * sizeof(__bf16)) {   // 16 MB
        opm_partial<<<32 * NSP, 512, 0, stream>>>(A, Bm, (__bf16*)d_ws, nullptr,
                                                  NSP, S_TOTAL / NSP, 1.0f);
        opm_reduce16<<<256, 256, 0, stream>>>((const __bf16*)d_ws, out);
    } else {
        // tiny-ws fallback: 32 blocks (8 batch x 4 jq), full K, f32 direct
        opm_partial<<<32, 512, 0, stream>>>(A, Bm, nullptr, out, 1, S_TOTAL, 1.0f / 8192.0f);
    }
}